// Round 8
// baseline (368.437 us; speedup 1.0000x reference)
//
#include <hip/hip_runtime.h>
#include <stdint.h>

#define SEQ 4096
#define INDIM 1024
#define NODEDIM 512
#define NH 8
#define HD 64
#define LSTR 72  // padded LDS row stride (ushorts): 144B -> 4-bank rotation per row

typedef __bf16 bf16x8 __attribute__((ext_vector_type(8)));
typedef float f32x4 __attribute__((ext_vector_type(4)));

#define GLOAD_LDS(gp, lp) \
    __builtin_amdgcn_global_load_lds( \
        (const __attribute__((address_space(1))) void*)(gp), \
        (__attribute__((address_space(3))) void*)(lp), 16, 0, 0)

__device__ __forceinline__ unsigned short f2bf(float f) {
    union { float f; uint32_t u; } v; v.f = f;
    uint32_t u = v.u;
    uint32_t r = (u + 0x7fffu + ((u >> 16) & 1u)) >> 16;  // RNE
    return (unsigned short)r;
}

__device__ __forceinline__ float fast_exp2(float x) {
    float r;
    asm volatile("v_exp_f32 %0, %1" : "=v"(r) : "v"(x));
    return r;
}

// ---------------------------------------------------------------- cvt fp32->bf16 (all tensors, one launch)
__global__ __launch_bounds__(256) void cvt_all(const float* __restrict__ emb,
                                               const float* __restrict__ Wq,
                                               const float* __restrict__ Wk,
                                               const float* __restrict__ Wv,
                                               const float* __restrict__ Wo,
                                               unsigned short* __restrict__ demb,
                                               unsigned short* __restrict__ dwqkv,
                                               unsigned short* __restrict__ dwo) {
    int b = blockIdx.x;
    const float* src;
    unsigned short* dst;
    int off;
    if (b < 4096)      { src = emb; dst = demb;            off = b; }
    else if (b < 4608) { src = Wq;  dst = dwqkv;           off = b - 4096; }
    else if (b < 5120) { src = Wk;  dst = dwqkv + 524288;  off = b - 4608; }
    else if (b < 5632) { src = Wv;  dst = dwqkv + 1048576; off = b - 5120; }
    else               { src = Wo;  dst = dwo;             off = b - 5632; }
    int i = (off * 256 + threadIdx.x) * 4;
    float4 v = *(const float4*)(src + i);
    ushort4 o;
    o.x = f2bf(v.x); o.y = f2bf(v.y); o.z = f2bf(v.z); o.w = f2bf(v.w);
    *(ushort4*)(dst + i) = o;
}

// ---------------------------------------------------------------- QKV GEMM (r5 form)
// C[4096,1536] = emb_bf16[4096,1024] @ Wqkv^T[1536,1024]; epilogue: +bias.
// blockIdx.y 0-3 -> Q [H,S,D], 4-7 -> K [H,S,D], 8-11 -> V transposed [H,D,S].
__global__ __launch_bounds__(256) void qkv_gemm(const unsigned short* __restrict__ A,
                                                const unsigned short* __restrict__ B,
                                                const float* __restrict__ bq,
                                                const float* __restrict__ bk,
                                                const float* __restrict__ bv,
                                                unsigned short* __restrict__ Qo,
                                                unsigned short* __restrict__ Ko,
                                                unsigned short* __restrict__ VTo) {
    __shared__ unsigned short As[128 * 32];
    __shared__ unsigned short Bs[128 * 32];
    __shared__ unsigned short Ts[128 * 40];  // V-transpose staging
    const int tid = threadIdx.x;
    const int lane = tid & 63, wave = tid >> 6;
    const int wm = wave >> 1, wn = wave & 1;
    const int quad = lane >> 4, l16 = lane & 15;
    const int m0 = blockIdx.x * 128;
    const int n0 = blockIdx.y * 128;

    const int srow = tid >> 2, sqq = tid & 3;

    f32x4 acc[4][4] = {};

    for (int k0 = 0; k0 < INDIM; k0 += 32) {
        __syncthreads();
        for (int i = 0; i < 2; ++i) {
            int row = srow + 64 * i;
            GLOAD_LDS(A + (size_t)(m0 + row) * INDIM + k0 + sqq * 8, &As[row * 32 + sqq * 8]);
            GLOAD_LDS(B + (size_t)(n0 + row) * INDIM + k0 + sqq * 8, &Bs[row * 32 + sqq * 8]);
        }
        __syncthreads();
        bf16x8 af[4], bf[4];
        for (int mi = 0; mi < 4; ++mi)
            af[mi] = *(const bf16x8*)&As[(wm * 64 + mi * 16 + l16) * 32 + quad * 8];
        for (int ni = 0; ni < 4; ++ni)
            bf[ni] = *(const bf16x8*)&Bs[(wn * 64 + ni * 16 + l16) * 32 + quad * 8];
        for (int mi = 0; mi < 4; ++mi)
            for (int ni = 0; ni < 4; ++ni)
                acc[mi][ni] = __builtin_amdgcn_mfma_f32_16x16x32_bf16(af[mi], bf[ni], acc[mi][ni], 0, 0, 0);
    }

    if (blockIdx.y < 8) {
        unsigned short* outp = (blockIdx.y < 4) ? Qo : Ko;
        const float* biasp = (blockIdx.y < 4) ? bq : bk;
        for (int mi = 0; mi < 4; ++mi)
            for (int ni = 0; ni < 4; ++ni)
                for (int r = 0; r < 4; ++r) {
                    int s = m0 + wm * 64 + mi * 16 + quad * 4 + r;
                    int n = n0 + wn * 64 + ni * 16 + l16;
                    int h = (n >> 6) & 7;
                    int dd = n & 63;
                    float v = acc[mi][ni][r] + biasp[n & 511];
                    outp[((size_t)h * SEQ + s) * HD + dd] = f2bf(v);
                }
    } else {
        for (int chunk = 0; chunk < 4; ++chunk) {
            const int cwm = chunk >> 1;
            const int milo = (chunk & 1) * 2;
            __syncthreads();
            if (wm == cwm) {
                for (int mi2 = 0; mi2 < 2; ++mi2) {
                    int mi = milo + mi2;
                    for (int ni = 0; ni < 4; ++ni) {
                        int ddf = wn * 64 + ni * 16 + l16;
                        float bias = bv[(n0 + ddf) & 511];
                        for (int r = 0; r < 4; ++r) {
                            int sl = mi2 * 16 + quad * 4 + r;
                            Ts[ddf * 40 + sl] = f2bf(acc[mi][ni][r] + bias);
                        }
                    }
                }
            }
            __syncthreads();
            for (int pass = 0; pass < 2; ++pass) {
                int c = pass * 256 + tid;
                int row = c >> 2, part = c & 3;
                int nfull = n0 + row;
                int h = (nfull >> 6) & 7, dd = nfull & 63;
                *(bf16x8*)(VTo + ((size_t)h * HD + dd) * SEQ + m0 + chunk * 32 + part * 8) =
                    *(const bf16x8*)&Ts[row * 40 + part * 8];
            }
        }
    }
}

// ---------------------------------------------------------------- flash attention (max-free, 32q/wave)
// Grid (32, 8, 2): 128-q-row tile, head, t-split. Each wave owns 32 q rows
// (2 x 16q MFMA blocks). K/V frag reads + staging are q-invariant, so doubling
// q per wave cuts LDS cycles per unit work ~33% (the r7-measured bottleneck).
__global__ __launch_bounds__(256, 4) void attn_kernel(const unsigned short* __restrict__ Q,
                                                      const unsigned short* __restrict__ K,
                                                      const unsigned short* __restrict__ VT,
                                                      const float* __restrict__ CM,
                                                      const float* __restrict__ Wc,
                                                      float* __restrict__ O0,
                                                      float* __restrict__ O1,
                                                      float* __restrict__ l0,
                                                      float* __restrict__ l1) {
    __shared__ unsigned short QPs[128 * LSTR];  // Q tile, then reused as P tile (wave-local rows)
    __shared__ unsigned short Ks[64 * LSTR];
    __shared__ unsigned short Vs[64 * LSTR];    // V^T tile: [d][t]
    const int tid = threadIdx.x;
    const int lane = tid & 63, wave = tid >> 6;
    const int quad = lane >> 4, l16 = lane & 15;
    const int h = blockIdx.y;
    const int q0 = blockIdx.x * 128;
    const int split = blockIdx.z;
    float* __restrict__ Op = split ? O1 : O0;
    float* __restrict__ lp = split ? l1 : l0;
    const float wch = Wc[h] * 0.125f * 1.44269504f;

    // stage Q tile (128 rows x 8 parts = 1024 tasks), scaled
    for (int i = 0; i < 4; ++i) {
        int c = tid + 256 * i;
        int row = c >> 3, part = c & 7;
        bf16x8 v = *(const bf16x8*)(Q + ((size_t)h * SEQ + q0 + row) * HD + part * 8);
        for (int j = 0; j < 8; ++j) v[j] = (__bf16)((float)v[j] * wch);
        *(bf16x8*)&QPs[row * LSTR + part * 8] = v;
    }

    const int tbeg = split * (SEQ / 2);
    const int tend = tbeg + SEQ / 2;

    const int srow0 = tid >> 3, spart = tid & 7;
    const int srow1 = (tid + 256) >> 3;
    const unsigned short* kp0 = K + ((size_t)h * SEQ + tbeg + srow0) * HD + spart * 8;
    const unsigned short* kp1 = K + ((size_t)h * SEQ + tbeg + srow1) * HD + spart * 8;
    const unsigned short* vp0 = VT + ((size_t)h * HD + srow0) * SEQ + tbeg + spart * 8;
    const unsigned short* vp1 = VT + ((size_t)h * HD + srow1) * SEQ + tbeg + spart * 8;
    bf16x8 kr0 = *(const bf16x8*)kp0;
    bf16x8 kr1 = *(const bf16x8*)kp1;
    bf16x8 vr0 = *(const bf16x8*)vp0;
    bf16x8 vr1 = *(const bf16x8*)vp1;

    __syncthreads();  // Q staged
    // hoist Q fragments: 2 q-blocks x 2 k-halves (read once; QPs rows reused for P)
    bf16x8 a[2][2];
    for (int mi = 0; mi < 2; ++mi) {
        a[mi][0] = *(const bf16x8*)&QPs[(wave * 32 + mi * 16 + l16) * LSTR + quad * 8];
        a[mi][1] = *(const bf16x8*)&QPs[(wave * 32 + mi * 16 + l16) * LSTR + 32 + quad * 8];
    }

    f32x4 O[2][4] = {};
    float l_part[2][4] = {};
    const float* cmbase0 = CM + (size_t)(q0 + wave * 32 + quad * 4) * SEQ + l16;
    const float* cmbase1 = cmbase0 + (size_t)16 * SEQ;

    for (int t0 = tbeg; t0 < tend; t0 += 64) {
        // contact-mask values for THIS tile (2 q-blocks x 4 r x 4 nt)
        float cmv[2][4][4];
        for (int r = 0; r < 4; ++r)
            for (int nt = 0; nt < 4; ++nt) {
                cmv[0][r][nt] = cmbase0[(size_t)r * SEQ + t0 + nt * 16];
                cmv[1][r][nt] = cmbase1[(size_t)r * SEQ + t0 + nt * 16];
            }

        __syncthreads();
        *(bf16x8*)&Ks[srow0 * LSTR + spart * 8] = kr0;
        *(bf16x8*)&Ks[srow1 * LSTR + spart * 8] = kr1;
        *(bf16x8*)&Vs[srow0 * LSTR + spart * 8] = vr0;
        *(bf16x8*)&Vs[srow1 * LSTR + spart * 8] = vr1;
        __syncthreads();

        if (t0 + 64 < tend) {
            kr0 = *(const bf16x8*)(kp0 + (size_t)(t0 + 64 - tbeg) * HD);
            kr1 = *(const bf16x8*)(kp1 + (size_t)(t0 + 64 - tbeg) * HD);
            vr0 = *(const bf16x8*)(vp0 + (t0 + 64 - tbeg));
            vr1 = *(const bf16x8*)(vp1 + (t0 + 64 - tbeg));
        }

        // ---- scores: Sc[32q x 64t] per wave; K frags shared across q-blocks
        f32x4 sc[2][4];
        for (int nt = 0; nt < 4; ++nt) {
            bf16x8 b0 = *(const bf16x8*)&Ks[(nt * 16 + l16) * LSTR + quad * 8];
            bf16x8 b1 = *(const bf16x8*)&Ks[(nt * 16 + l16) * LSTR + 32 + quad * 8];
            for (int mi = 0; mi < 2; ++mi) {
                f32x4 z = {0.f, 0.f, 0.f, 0.f};
                z = __builtin_amdgcn_mfma_f32_16x16x32_bf16(a[mi][0], b0, z, 0, 0, 0);
                z = __builtin_amdgcn_mfma_f32_16x16x32_bf16(a[mi][1], b1, z, 0, 0, 0);
                sc[mi][nt] = z;
            }
        }

        // ---- max-free softmax: P = 2^(sc*cm'), trunc-to-bf16, lane-local l
        for (int mi = 0; mi < 2; ++mi)
            for (int r = 0; r < 4; ++r)
                for (int nt = 0; nt < 4; ++nt) {
                    float pv = fast_exp2(sc[mi][nt][r] * cmv[mi][r][nt]);
                    l_part[mi][r] += pv;
                    union { float f; uint32_t u; } pu; pu.f = pv;
                    QPs[(wave * 32 + mi * 16 + quad * 4 + r) * LSTR + nt * 16 + l16] =
                        (unsigned short)(pu.u >> 16);
                }

        // wave-internal LDS RAW on P rows (wave-local; no barrier needed)
        asm volatile("s_waitcnt lgkmcnt(0)" ::: "memory");

        // ---- PV: O[32q x 64d] += P[32q x 64t] * V[64t x 64d]; V frags shared
        bf16x8 pa[2][2];
        for (int mi = 0; mi < 2; ++mi) {
            pa[mi][0] = *(const bf16x8*)&QPs[(wave * 32 + mi * 16 + l16) * LSTR + quad * 8];
            pa[mi][1] = *(const bf16x8*)&QPs[(wave * 32 + mi * 16 + l16) * LSTR + 32 + quad * 8];
        }
        for (int nt = 0; nt < 4; ++nt) {
            bf16x8 vb0 = *(const bf16x8*)&Vs[(nt * 16 + l16) * LSTR + quad * 8];
            bf16x8 vb1 = *(const bf16x8*)&Vs[(nt * 16 + l16) * LSTR + 32 + quad * 8];
            for (int mi = 0; mi < 2; ++mi) {
                f32x4 o = O[mi][nt];
                o = __builtin_amdgcn_mfma_f32_16x16x32_bf16(pa[mi][0], vb0, o, 0, 0, 0);
                o = __builtin_amdgcn_mfma_f32_16x16x32_bf16(pa[mi][1], vb1, o, 0, 0, 0);
                O[mi][nt] = o;
            }
        }
    }

    // epilogue: reduce l across the 16 t-lanes of each row, store partials
    for (int mi = 0; mi < 2; ++mi)
        for (int r = 0; r < 4; ++r) {
            float s = l_part[mi][r];
            for (int off = 1; off < 16; off <<= 1) s += __shfl_xor(s, off);
            l_part[mi][r] = s;
        }
    if (l16 == 0)
        for (int mi = 0; mi < 2; ++mi)
            for (int r = 0; r < 4; ++r)
                lp[(size_t)h * SEQ + q0 + wave * 32 + mi * 16 + quad * 4 + r] = l_part[mi][r];
    for (int mi = 0; mi < 2; ++mi)
        for (int nt = 0; nt < 4; ++nt)
            for (int r = 0; r < 4; ++r) {
                int sg = q0 + wave * 32 + mi * 16 + quad * 4 + r;
                Op[((size_t)h * SEQ + sg) * HD + nt * 16 + l16] = O[mi][nt][r];
            }
}

// ---------------------------------------------------------------- combine splits -> AO bf16
__global__ __launch_bounds__(256) void combine_kernel(const float* __restrict__ O0,
                                                      const float* __restrict__ O1,
                                                      const float* __restrict__ l0,
                                                      const float* __restrict__ l1,
                                                      unsigned short* __restrict__ AO) {
    int idx = blockIdx.x * 256 + threadIdx.x;
    int e = idx * 4;
    int row = e >> 6;  // h*SEQ + s
    float4 a = *(const float4*)(O0 + e);
    float4 b = *(const float4*)(O1 + e);
    float linv = 1.f / (l0[row] + l1[row]);
    ushort4 o;
    o.x = f2bf((a.x + b.x) * linv);
    o.y = f2bf((a.y + b.y) * linv);
    o.z = f2bf((a.z + b.z) * linv);
    o.w = f2bf((a.w + b.w) * linv);
    *(ushort4*)(AO + e) = o;
}

// ---------------------------------------------------------------- output GEMM + residual (r5 form)
__global__ __launch_bounds__(256) void out_gemm(const unsigned short* __restrict__ A,
                                                const unsigned short* __restrict__ B,
                                                const float* __restrict__ bo,
                                                const float* __restrict__ emb,
                                                float* __restrict__ X) {
    __shared__ unsigned short As[64 * 32];
    __shared__ unsigned short Bs[128 * 32];
    const int tid = threadIdx.x;
    const int lane = tid & 63, wave = tid >> 6;
    const int quad = lane >> 4, l16 = lane & 15;
    const int m0 = blockIdx.x * 64;
    const int n0 = blockIdx.y * 128;

    const int srow = tid >> 2, sqq = tid & 3;

    f32x4 acc[8] = {};

    for (int k0 = 0; k0 < NODEDIM; k0 += 32) {
        __syncthreads();
        GLOAD_LDS(A + (size_t)(m0 + srow) * NODEDIM + k0 + sqq * 8, &As[srow * 32 + sqq * 8]);
        for (int i = 0; i < 2; ++i) {
            int row = srow + 64 * i;
            GLOAD_LDS(B + (size_t)(n0 + row) * NODEDIM + k0 + sqq * 8, &Bs[row * 32 + sqq * 8]);
        }
        __syncthreads();
        bf16x8 af = *(const bf16x8*)&As[(wave * 16 + l16) * 32 + quad * 8];
        for (int ni = 0; ni < 8; ++ni) {
            bf16x8 bf = *(const bf16x8*)&Bs[(ni * 16 + l16) * 32 + quad * 8];
            acc[ni] = __builtin_amdgcn_mfma_f32_16x16x32_bf16(af, bf, acc[ni], 0, 0, 0);
        }
    }

    for (int ni = 0; ni < 8; ++ni)
        for (int r = 0; r < 4; ++r) {
            int s = m0 + wave * 16 + quad * 4 + r;
            int n = n0 + ni * 16 + l16;
            float v = acc[ni][r] + bo[n] + emb[(size_t)s * INDIM + n];
            X[(size_t)s * NODEDIM + n] = v;
        }
}

// ---------------------------------------------------------------- LayerNorm
__global__ __launch_bounds__(256) void ln_kernel(const float* __restrict__ X,
                                                 const float* __restrict__ gamma,
                                                 const float* __restrict__ beta,
                                                 float* __restrict__ out) {
    const int s = blockIdx.x;
    const int n = threadIdx.x * 2;
    float2 v = *(const float2*)&X[(size_t)s * NODEDIM + n];
    float sum = v.x + v.y;
    float sq = v.x * v.x + v.y * v.y;
    for (int off = 32; off > 0; off >>= 1) {
        sum += __shfl_down(sum, off);
        sq += __shfl_down(sq, off);
    }
    __shared__ float ssum[4], ssq[4];
    const int wave = threadIdx.x >> 6, lane = threadIdx.x & 63;
    if (lane == 0) { ssum[wave] = sum; ssq[wave] = sq; }
    __syncthreads();
    float tsum = ssum[0] + ssum[1] + ssum[2] + ssum[3];
    float tsq = ssq[0] + ssq[1] + ssq[2] + ssq[3];
    float mu = tsum * (1.f / 512.f);
    float var = tsq * (1.f / 512.f) - mu * mu;
    float rstd = rsqrtf(var + 1e-5f);
    float2 g = *(const float2*)&gamma[n];
    float2 b = *(const float2*)&beta[n];
    float2 o;
    o.x = (v.x - mu) * rstd * g.x + b.x;
    o.y = (v.y - mu) * rstd * g.y + b.y;
    *(float2*)&out[(size_t)s * NODEDIM + n] = o;
}

// ---------------------------------------------------------------- launch
extern "C" void kernel_launch(void* const* d_in, const int* in_sizes, int n_in,
                              void* d_out, int out_size, void* d_ws, size_t ws_size,
                              hipStream_t stream) {
    const float* emb = (const float*)d_in[0];
    const float* cm  = (const float*)d_in[1];
    const float* Wq  = (const float*)d_in[2];
    const float* bq  = (const float*)d_in[3];
    const float* Wk  = (const float*)d_in[4];
    const float* bk  = (const float*)d_in[5];
    const float* Wv  = (const float*)d_in[6];
    const float* bv  = (const float*)d_in[7];
    const float* Wc  = (const float*)d_in[8];
    const float* Wo  = (const float*)d_in[9];
    const float* bo  = (const float*)d_in[10];
    const float* gamma = (const float*)d_in[11];
    const float* beta  = (const float*)d_in[12];
    float* out = (float*)d_out;

    unsigned short* ws = (unsigned short*)d_ws;
    unsigned short* emb_bf  = ws;                       // 8 MB (dead after qkv_gemm)
    unsigned short* wqkv_bf = emb_bf + 4194304;         // 3 MB (dead after qkv_gemm)
    unsigned short* wo_bf   = wqkv_bf + 1572864;        // 0.5 MB
    unsigned short* Qb  = wo_bf + 262144;               // [H,S,D] bf16
    unsigned short* Kb  = Qb + 2097152;                 // [H,S,D] bf16
    unsigned short* VTb = Kb + 2097152;                 // [H,D,S] bf16
    unsigned short* AOb = VTb + 2097152;                // [H,S,D] bf16
    float* X = (float*)(AOb + 2097152);                 // 8 MB f32
    // attention split partials, overlaid on dead regions:
    float* O0 = (float*)emb_bf;                         // 8 MB (after qkv_gemm done)
    float* O1 = X;                                      // 8 MB (X written later by out_gemm)
    float* l0 = (float*)wqkv_bf;                        // 128 KB
    float* l1 = l0 + NH * SEQ;                          // 128 KB

    cvt_all<<<5888, 256, 0, stream>>>(emb, Wq, Wk, Wv, Wo, emb_bf, wqkv_bf, wo_bf);

    qkv_gemm<<<dim3(32, 12), 256, 0, stream>>>(emb_bf, wqkv_bf, bq, bk, bv, Qb, Kb, VTb);
    attn_kernel<<<dim3(32, 8, 2), 256, 0, stream>>>(Qb, Kb, VTb, cm, Wc, O0, O1, l0, l1);
    combine_kernel<<<2048, 256, 0, stream>>>(O0, O1, l0, l1, AOb);
    out_gemm<<<dim3(64, 4), 256, 0, stream>>>(AOb, wo_bf, bo, emb, X);
    ln_kernel<<<4096, 256, 0, stream>>>(X, gamma, beta, out);
}

// Round 9
// 256.934 us; speedup vs baseline: 1.4340x; 1.4340x over previous
//
#include <hip/hip_runtime.h>
#include <stdint.h>

#define SEQ 4096
#define INDIM 1024
#define NODEDIM 512
#define NH 8
#define HD 64
#define LSTR 72  // padded LDS row stride (ushorts): 144B -> 4-bank rotation per row

typedef __bf16 bf16x8 __attribute__((ext_vector_type(8)));
typedef float f32x4 __attribute__((ext_vector_type(4)));

#define GLOAD_LDS(gp, lp) \
    __builtin_amdgcn_global_load_lds( \
        (const __attribute__((address_space(1))) void*)(gp), \
        (__attribute__((address_space(3))) void*)(lp), 16, 0, 0)

__device__ __forceinline__ unsigned short f2bf(float f) {
    union { float f; uint32_t u; } v; v.f = f;
    uint32_t u = v.u;
    uint32_t r = (u + 0x7fffu + ((u >> 16) & 1u)) >> 16;  // RNE
    return (unsigned short)r;
}

__device__ __forceinline__ float fast_exp2(float x) {
    float r;
    asm volatile("v_exp_f32 %0, %1" : "=v"(r) : "v"(x));
    return r;
}

// ---------------------------------------------------------------- cvt fp32->bf16 (all tensors, one launch)
__global__ __launch_bounds__(256) void cvt_all(const float* __restrict__ emb,
                                               const float* __restrict__ Wq,
                                               const float* __restrict__ Wk,
                                               const float* __restrict__ Wv,
                                               const float* __restrict__ Wo,
                                               unsigned short* __restrict__ demb,
                                               unsigned short* __restrict__ dwqkv,
                                               unsigned short* __restrict__ dwo) {
    int b = blockIdx.x;
    const float* src;
    unsigned short* dst;
    int off;
    if (b < 4096)      { src = emb; dst = demb;            off = b; }
    else if (b < 4608) { src = Wq;  dst = dwqkv;           off = b - 4096; }
    else if (b < 5120) { src = Wk;  dst = dwqkv + 524288;  off = b - 4608; }
    else if (b < 5632) { src = Wv;  dst = dwqkv + 1048576; off = b - 5120; }
    else               { src = Wo;  dst = dwo;             off = b - 5632; }
    int i = (off * 256 + threadIdx.x) * 4;
    float4 v = *(const float4*)(src + i);
    ushort4 o;
    o.x = f2bf(v.x); o.y = f2bf(v.y); o.z = f2bf(v.z); o.w = f2bf(v.w);
    *(ushort4*)(dst + i) = o;
}

// ---------------------------------------------------------------- QKV GEMM (r5 form)
__global__ __launch_bounds__(256) void qkv_gemm(const unsigned short* __restrict__ A,
                                                const unsigned short* __restrict__ B,
                                                const float* __restrict__ bq,
                                                const float* __restrict__ bk,
                                                const float* __restrict__ bv,
                                                unsigned short* __restrict__ Qo,
                                                unsigned short* __restrict__ Ko,
                                                unsigned short* __restrict__ VTo) {
    __shared__ unsigned short As[128 * 32];
    __shared__ unsigned short Bs[128 * 32];
    __shared__ unsigned short Ts[128 * 40];  // V-transpose staging
    const int tid = threadIdx.x;
    const int lane = tid & 63, wave = tid >> 6;
    const int wm = wave >> 1, wn = wave & 1;
    const int quad = lane >> 4, l16 = lane & 15;
    const int m0 = blockIdx.x * 128;
    const int n0 = blockIdx.y * 128;

    const int srow = tid >> 2, sqq = tid & 3;

    f32x4 acc[4][4] = {};

    for (int k0 = 0; k0 < INDIM; k0 += 32) {
        __syncthreads();
        for (int i = 0; i < 2; ++i) {
            int row = srow + 64 * i;
            GLOAD_LDS(A + (size_t)(m0 + row) * INDIM + k0 + sqq * 8, &As[row * 32 + sqq * 8]);
            GLOAD_LDS(B + (size_t)(n0 + row) * INDIM + k0 + sqq * 8, &Bs[row * 32 + sqq * 8]);
        }
        __syncthreads();
        bf16x8 af[4], bf[4];
        for (int mi = 0; mi < 4; ++mi)
            af[mi] = *(const bf16x8*)&As[(wm * 64 + mi * 16 + l16) * 32 + quad * 8];
        for (int ni = 0; ni < 4; ++ni)
            bf[ni] = *(const bf16x8*)&Bs[(wn * 64 + ni * 16 + l16) * 32 + quad * 8];
        for (int mi = 0; mi < 4; ++mi)
            for (int ni = 0; ni < 4; ++ni)
                acc[mi][ni] = __builtin_amdgcn_mfma_f32_16x16x32_bf16(af[mi], bf[ni], acc[mi][ni], 0, 0, 0);
    }

    if (blockIdx.y < 8) {
        unsigned short* outp = (blockIdx.y < 4) ? Qo : Ko;
        const float* biasp = (blockIdx.y < 4) ? bq : bk;
        for (int mi = 0; mi < 4; ++mi)
            for (int ni = 0; ni < 4; ++ni)
                for (int r = 0; r < 4; ++r) {
                    int s = m0 + wm * 64 + mi * 16 + quad * 4 + r;
                    int n = n0 + wn * 64 + ni * 16 + l16;
                    int h = (n >> 6) & 7;
                    int dd = n & 63;
                    float v = acc[mi][ni][r] + biasp[n & 511];
                    outp[((size_t)h * SEQ + s) * HD + dd] = f2bf(v);
                }
    } else {
        for (int chunk = 0; chunk < 4; ++chunk) {
            const int cwm = chunk >> 1;
            const int milo = (chunk & 1) * 2;
            __syncthreads();
            if (wm == cwm) {
                for (int mi2 = 0; mi2 < 2; ++mi2) {
                    int mi = milo + mi2;
                    for (int ni = 0; ni < 4; ++ni) {
                        int ddf = wn * 64 + ni * 16 + l16;
                        float bias = bv[(n0 + ddf) & 511];
                        for (int r = 0; r < 4; ++r) {
                            int sl = mi2 * 16 + quad * 4 + r;
                            Ts[ddf * 40 + sl] = f2bf(acc[mi][ni][r] + bias);
                        }
                    }
                }
            }
            __syncthreads();
            for (int pass = 0; pass < 2; ++pass) {
                int c = pass * 256 + tid;
                int row = c >> 2, part = c & 3;
                int nfull = n0 + row;
                int h = (nfull >> 6) & 7, dd = nfull & 63;
                *(bf16x8*)(VTo + ((size_t)h * HD + dd) * SEQ + m0 + chunk * 32 + part * 8) =
                    *(const bf16x8*)&Ts[row * 40 + part * 8];
            }
        }
    }
}

// ---------------------------------------------------------------- flash attention (max-free, 32q/wave)
// Grid (32, 8, 2). Identical to round 8 EXCEPT __launch_bounds__(256, 2):
// r8's (256,4) capped VGPRs at 64 -> ~150 live regs spilled to scratch/HBM
// (WRITE_SIZE 16.6 -> 233 MB, MfmaUtil 7%). 256-VGPR budget removes the spill;
// LDS (36.9 KB) limits blocks/CU anyway.
__global__ __launch_bounds__(256, 2) void attn_kernel(const unsigned short* __restrict__ Q,
                                                      const unsigned short* __restrict__ K,
                                                      const unsigned short* __restrict__ VT,
                                                      const float* __restrict__ CM,
                                                      const float* __restrict__ Wc,
                                                      float* __restrict__ O0,
                                                      float* __restrict__ O1,
                                                      float* __restrict__ l0,
                                                      float* __restrict__ l1) {
    __shared__ unsigned short QPs[128 * LSTR];  // Q tile, then reused as P tile (wave-local rows)
    __shared__ unsigned short Ks[64 * LSTR];
    __shared__ unsigned short Vs[64 * LSTR];    // V^T tile: [d][t]
    const int tid = threadIdx.x;
    const int lane = tid & 63, wave = tid >> 6;
    const int quad = lane >> 4, l16 = lane & 15;
    const int h = blockIdx.y;
    const int q0 = blockIdx.x * 128;
    const int split = blockIdx.z;
    float* __restrict__ Op = split ? O1 : O0;
    float* __restrict__ lp = split ? l1 : l0;
    const float wch = Wc[h] * 0.125f * 1.44269504f;

    // stage Q tile (128 rows x 8 parts = 1024 tasks), scaled
    for (int i = 0; i < 4; ++i) {
        int c = tid + 256 * i;
        int row = c >> 3, part = c & 7;
        bf16x8 v = *(const bf16x8*)(Q + ((size_t)h * SEQ + q0 + row) * HD + part * 8);
        for (int j = 0; j < 8; ++j) v[j] = (__bf16)((float)v[j] * wch);
        *(bf16x8*)&QPs[row * LSTR + part * 8] = v;
    }

    const int tbeg = split * (SEQ / 2);
    const int tend = tbeg + SEQ / 2;

    const int srow0 = tid >> 3, spart = tid & 7;
    const int srow1 = (tid + 256) >> 3;
    const unsigned short* kp0 = K + ((size_t)h * SEQ + tbeg + srow0) * HD + spart * 8;
    const unsigned short* kp1 = K + ((size_t)h * SEQ + tbeg + srow1) * HD + spart * 8;
    const unsigned short* vp0 = VT + ((size_t)h * HD + srow0) * SEQ + tbeg + spart * 8;
    const unsigned short* vp1 = VT + ((size_t)h * HD + srow1) * SEQ + tbeg + spart * 8;
    bf16x8 kr0 = *(const bf16x8*)kp0;
    bf16x8 kr1 = *(const bf16x8*)kp1;
    bf16x8 vr0 = *(const bf16x8*)vp0;
    bf16x8 vr1 = *(const bf16x8*)vp1;

    __syncthreads();  // Q staged
    // hoist Q fragments: 2 q-blocks x 2 k-halves (read once; QPs rows reused for P)
    bf16x8 a[2][2];
    for (int mi = 0; mi < 2; ++mi) {
        a[mi][0] = *(const bf16x8*)&QPs[(wave * 32 + mi * 16 + l16) * LSTR + quad * 8];
        a[mi][1] = *(const bf16x8*)&QPs[(wave * 32 + mi * 16 + l16) * LSTR + 32 + quad * 8];
    }

    f32x4 O[2][4] = {};
    float l_part[2][4] = {};
    const float* cmbase0 = CM + (size_t)(q0 + wave * 32 + quad * 4) * SEQ + l16;
    const float* cmbase1 = cmbase0 + (size_t)16 * SEQ;

    for (int t0 = tbeg; t0 < tend; t0 += 64) {
        // contact-mask values for THIS tile (2 q-blocks x 4 r x 4 nt)
        float cmv[2][4][4];
        for (int r = 0; r < 4; ++r)
            for (int nt = 0; nt < 4; ++nt) {
                cmv[0][r][nt] = cmbase0[(size_t)r * SEQ + t0 + nt * 16];
                cmv[1][r][nt] = cmbase1[(size_t)r * SEQ + t0 + nt * 16];
            }

        __syncthreads();
        *(bf16x8*)&Ks[srow0 * LSTR + spart * 8] = kr0;
        *(bf16x8*)&Ks[srow1 * LSTR + spart * 8] = kr1;
        *(bf16x8*)&Vs[srow0 * LSTR + spart * 8] = vr0;
        *(bf16x8*)&Vs[srow1 * LSTR + spart * 8] = vr1;
        __syncthreads();

        if (t0 + 64 < tend) {
            kr0 = *(const bf16x8*)(kp0 + (size_t)(t0 + 64 - tbeg) * HD);
            kr1 = *(const bf16x8*)(kp1 + (size_t)(t0 + 64 - tbeg) * HD);
            vr0 = *(const bf16x8*)(vp0 + (t0 + 64 - tbeg));
            vr1 = *(const bf16x8*)(vp1 + (t0 + 64 - tbeg));
        }

        // ---- scores: Sc[32q x 64t] per wave; K frags shared across q-blocks
        f32x4 sc[2][4];
        for (int nt = 0; nt < 4; ++nt) {
            bf16x8 b0 = *(const bf16x8*)&Ks[(nt * 16 + l16) * LSTR + quad * 8];
            bf16x8 b1 = *(const bf16x8*)&Ks[(nt * 16 + l16) * LSTR + 32 + quad * 8];
            for (int mi = 0; mi < 2; ++mi) {
                f32x4 z = {0.f, 0.f, 0.f, 0.f};
                z = __builtin_amdgcn_mfma_f32_16x16x32_bf16(a[mi][0], b0, z, 0, 0, 0);
                z = __builtin_amdgcn_mfma_f32_16x16x32_bf16(a[mi][1], b1, z, 0, 0, 0);
                sc[mi][nt] = z;
            }
        }

        // ---- max-free softmax: P = 2^(sc*cm'), trunc-to-bf16, lane-local l
        for (int mi = 0; mi < 2; ++mi)
            for (int r = 0; r < 4; ++r)
                for (int nt = 0; nt < 4; ++nt) {
                    float pv = fast_exp2(sc[mi][nt][r] * cmv[mi][r][nt]);
                    l_part[mi][r] += pv;
                    union { float f; uint32_t u; } pu; pu.f = pv;
                    QPs[(wave * 32 + mi * 16 + quad * 4 + r) * LSTR + nt * 16 + l16] =
                        (unsigned short)(pu.u >> 16);
                }

        // wave-internal LDS RAW on P rows (wave-local; no barrier needed)
        asm volatile("s_waitcnt lgkmcnt(0)" ::: "memory");

        // ---- PV: O[32q x 64d] += P[32q x 64t] * V[64t x 64d]; V frags shared
        bf16x8 pa[2][2];
        for (int mi = 0; mi < 2; ++mi) {
            pa[mi][0] = *(const bf16x8*)&QPs[(wave * 32 + mi * 16 + l16) * LSTR + quad * 8];
            pa[mi][1] = *(const bf16x8*)&QPs[(wave * 32 + mi * 16 + l16) * LSTR + 32 + quad * 8];
        }
        for (int nt = 0; nt < 4; ++nt) {
            bf16x8 vb0 = *(const bf16x8*)&Vs[(nt * 16 + l16) * LSTR + quad * 8];
            bf16x8 vb1 = *(const bf16x8*)&Vs[(nt * 16 + l16) * LSTR + 32 + quad * 8];
            for (int mi = 0; mi < 2; ++mi) {
                f32x4 o = O[mi][nt];
                o = __builtin_amdgcn_mfma_f32_16x16x32_bf16(pa[mi][0], vb0, o, 0, 0, 0);
                o = __builtin_amdgcn_mfma_f32_16x16x32_bf16(pa[mi][1], vb1, o, 0, 0, 0);
                O[mi][nt] = o;
            }
        }
    }

    // epilogue: reduce l across the 16 t-lanes of each row, store partials
    for (int mi = 0; mi < 2; ++mi)
        for (int r = 0; r < 4; ++r) {
            float s = l_part[mi][r];
            for (int off = 1; off < 16; off <<= 1) s += __shfl_xor(s, off);
            l_part[mi][r] = s;
        }
    if (l16 == 0)
        for (int mi = 0; mi < 2; ++mi)
            for (int r = 0; r < 4; ++r)
                lp[(size_t)h * SEQ + q0 + wave * 32 + mi * 16 + quad * 4 + r] = l_part[mi][r];
    for (int mi = 0; mi < 2; ++mi)
        for (int nt = 0; nt < 4; ++nt)
            for (int r = 0; r < 4; ++r) {
                int sg = q0 + wave * 32 + mi * 16 + quad * 4 + r;
                Op[((size_t)h * SEQ + sg) * HD + nt * 16 + l16] = O[mi][nt][r];
            }
}

// ---------------------------------------------------------------- combine splits -> AO bf16
__global__ __launch_bounds__(256) void combine_kernel(const float* __restrict__ O0,
                                                      const float* __restrict__ O1,
                                                      const float* __restrict__ l0,
                                                      const float* __restrict__ l1,
                                                      unsigned short* __restrict__ AO) {
    int idx = blockIdx.x * 256 + threadIdx.x;
    int e = idx * 4;
    int row = e >> 6;  // h*SEQ + s
    float4 a = *(const float4*)(O0 + e);
    float4 b = *(const float4*)(O1 + e);
    float linv = 1.f / (l0[row] + l1[row]);
    ushort4 o;
    o.x = f2bf((a.x + b.x) * linv);
    o.y = f2bf((a.y + b.y) * linv);
    o.z = f2bf((a.z + b.z) * linv);
    o.w = f2bf((a.w + b.w) * linv);
    *(ushort4*)(AO + e) = o;
}

// ---------------------------------------------------------------- output GEMM + residual (r5 form)
__global__ __launch_bounds__(256) void out_gemm(const unsigned short* __restrict__ A,
                                                const unsigned short* __restrict__ B,
                                                const float* __restrict__ bo,
                                                const float* __restrict__ emb,
                                                float* __restrict__ X) {
    __shared__ unsigned short As[64 * 32];
    __shared__ unsigned short Bs[128 * 32];
    const int tid = threadIdx.x;
    const int lane = tid & 63, wave = tid >> 6;
    const int quad = lane >> 4, l16 = lane & 15;
    const int m0 = blockIdx.x * 64;
    const int n0 = blockIdx.y * 128;

    const int srow = tid >> 2, sqq = tid & 3;

    f32x4 acc[8] = {};

    for (int k0 = 0; k0 < NODEDIM; k0 += 32) {
        __syncthreads();
        GLOAD_LDS(A + (size_t)(m0 + srow) * NODEDIM + k0 + sqq * 8, &As[srow * 32 + sqq * 8]);
        for (int i = 0; i < 2; ++i) {
            int row = srow + 64 * i;
            GLOAD_LDS(B + (size_t)(n0 + row) * NODEDIM + k0 + sqq * 8, &Bs[row * 32 + sqq * 8]);
        }
        __syncthreads();
        bf16x8 af = *(const bf16x8*)&As[(wave * 16 + l16) * 32 + quad * 8];
        for (int ni = 0; ni < 8; ++ni) {
            bf16x8 bf = *(const bf16x8*)&Bs[(ni * 16 + l16) * 32 + quad * 8];
            acc[ni] = __builtin_amdgcn_mfma_f32_16x16x32_bf16(af, bf, acc[ni], 0, 0, 0);
        }
    }

    for (int ni = 0; ni < 8; ++ni)
        for (int r = 0; r < 4; ++r) {
            int s = m0 + wave * 16 + quad * 4 + r;
            int n = n0 + ni * 16 + l16;
            float v = acc[ni][r] + bo[n] + emb[(size_t)s * INDIM + n];
            X[(size_t)s * NODEDIM + n] = v;
        }
}

// ---------------------------------------------------------------- LayerNorm
__global__ __launch_bounds__(256) void ln_kernel(const float* __restrict__ X,
                                                 const float* __restrict__ gamma,
                                                 const float* __restrict__ beta,
                                                 float* __restrict__ out) {
    const int s = blockIdx.x;
    const int n = threadIdx.x * 2;
    float2 v = *(const float2*)&X[(size_t)s * NODEDIM + n];
    float sum = v.x + v.y;
    float sq = v.x * v.x + v.y * v.y;
    for (int off = 32; off > 0; off >>= 1) {
        sum += __shfl_down(sum, off);
        sq += __shfl_down(sq, off);
    }
    __shared__ float ssum[4], ssq[4];
    const int wave = threadIdx.x >> 6, lane = threadIdx.x & 63;
    if (lane == 0) { ssum[wave] = sum; ssq[wave] = sq; }
    __syncthreads();
    float tsum = ssum[0] + ssum[1] + ssum[2] + ssum[3];
    float tsq = ssq[0] + ssq[1] + ssq[2] + ssq[3];
    float mu = tsum * (1.f / 512.f);
    float var = tsq * (1.f / 512.f) - mu * mu;
    float rstd = rsqrtf(var + 1e-5f);
    float2 g = *(const float2*)&gamma[n];
    float2 b = *(const float2*)&beta[n];
    float2 o;
    o.x = (v.x - mu) * rstd * g.x + b.x;
    o.y = (v.y - mu) * rstd * g.y + b.y;
    *(float2*)&out[(size_t)s * NODEDIM + n] = o;
}

// ---------------------------------------------------------------- launch
extern "C" void kernel_launch(void* const* d_in, const int* in_sizes, int n_in,
                              void* d_out, int out_size, void* d_ws, size_t ws_size,
                              hipStream_t stream) {
    const float* emb = (const float*)d_in[0];
    const float* cm  = (const float*)d_in[1];
    const float* Wq  = (const float*)d_in[2];
    const float* bq  = (const float*)d_in[3];
    const float* Wk  = (const float*)d_in[4];
    const float* bk  = (const float*)d_in[5];
    const float* Wv  = (const float*)d_in[6];
    const float* bv  = (const float*)d_in[7];
    const float* Wc  = (const float*)d_in[8];
    const float* Wo  = (const float*)d_in[9];
    const float* bo  = (const float*)d_in[10];
    const float* gamma = (const float*)d_in[11];
    const float* beta  = (const float*)d_in[12];
    float* out = (float*)d_out;

    unsigned short* ws = (unsigned short*)d_ws;
    unsigned short* emb_bf  = ws;                       // 8 MB (dead after qkv_gemm)
    unsigned short* wqkv_bf = emb_bf + 4194304;         // 3 MB (dead after qkv_gemm)
    unsigned short* wo_bf   = wqkv_bf + 1572864;        // 0.5 MB
    unsigned short* Qb  = wo_bf + 262144;               // [H,S,D] bf16
    unsigned short* Kb  = Qb + 2097152;                 // [H,S,D] bf16
    unsigned short* VTb = Kb + 2097152;                 // [H,D,S] bf16
    unsigned short* AOb = VTb + 2097152;                // [H,S,D] bf16
    float* X = (float*)(AOb + 2097152);                 // 8 MB f32
    // attention split partials, overlaid on dead regions:
    float* O0 = (float*)emb_bf;                         // 8 MB (after qkv_gemm done)
    float* O1 = X;                                      // 8 MB (X written later by out_gemm)
    float* l0 = (float*)wqkv_bf;                        // 128 KB
    float* l1 = l0 + NH * SEQ;                          // 128 KB

    cvt_all<<<5888, 256, 0, stream>>>(emb, Wq, Wk, Wv, Wo, emb_bf, wqkv_bf, wo_bf);

    qkv_gemm<<<dim3(32, 12), 256, 0, stream>>>(emb_bf, wqkv_bf, bq, bk, bv, Qb, Kb, VTb);
    attn_kernel<<<dim3(32, 8, 2), 256, 0, stream>>>(Qb, Kb, VTb, cm, Wc, O0, O1, l0, l1);
    combine_kernel<<<2048, 256, 0, stream>>>(O0, O1, l0, l1, AOb);
    out_gemm<<<dim3(64, 4), 256, 0, stream>>>(AOb, wo_bf, bo, emb, X);
    ln_kernel<<<4096, 256, 0, stream>>>(X, gamma, beta, out);
}